// Round 19
// baseline (13.013 us; speedup 1.0000x reference)
//
#include <hip/hip_runtime.h>
#include <hip/hip_bf16.h>
#include <hip/hip_fp16.h>

// Problem: B=16, N=256, F=64, H=64
// out[b,i,j] = (i==j) ? 1 : sigmoid( sum_h relu(a[b,i,h]+c[b,j,h]) * w2[h] + b2 )
// a = hs @ w1[:, :64]^T + b1, c = hs @ w1[:, 64:]^T
//
// Round-19: r16 (best, 12.06us) exact structure; micro-cuts only:
// bias folded into acc init, diagonal select only in on-diagonal blocks,
// output base precomputed. Stagger (r18, neutral) reverted.

#define Nn 256
#define Fd 64
#define Hd 64

typedef _Float16 h2v    __attribute__((ext_vector_type(2)));
typedef __fp16   fp16x2 __attribute__((ext_vector_type(2)));
typedef _Float16 f16x8  __attribute__((ext_vector_type(8)));
typedef float    f32x4  __attribute__((ext_vector_type(4)));
union H2   { h2v v; fp16x2 p; unsigned int u; };
union U4F8 { uint4 u; f16x8 v; };
union HS1  { _Float16 h; unsigned short s; };

__global__ __launch_bounds__(512) void fused_kernel(
    const float* __restrict__ hs, const float* __restrict__ w1,
    const float* __restrict__ b1, const float* __restrict__ w2,
    const float* __restrict__ b2, float* __restrict__ out) {
  __shared__ uint2 w1s[64][32];   // 16 KB: w1 f16, row h, chunk c at c^(h&15)
  __shared__ uint2 hsI[64][16];   //  8 KB: hs i-rows f16, chunk c at c^(r&7)
  __shared__ uint2 hsJ[64][16];   //  8 KB: hs j-rows f16
  __shared__ uint4 aT[64][8];     //  4 KB: a-tile f16 (pair layout)
  __shared__ uint4 cT[64][8];     //  4 KB: c-tile f16
  __shared__ unsigned int w2h[32];

  const int t  = threadIdx.x;
  const int b  = blockIdx.z;
  const int i0 = blockIdx.y * 64;
  const int j0 = blockIdx.x * 64;

  // ---- stage w1 (64x128 f32 -> f16 LDS), coalesced ----
  {
    const float4* w14 = (const float4*)w1;
#pragma unroll
    for (int p = 0; p < 4; ++p) {
      const int k4 = p * 512 + t;            // 0..2047
      const int r = k4 >> 5, col4 = k4 & 31;
      const float4 v = w14[k4];
      H2 lo, hi;
      lo.p = __builtin_amdgcn_cvt_pkrtz(v.x, v.y);
      hi.p = __builtin_amdgcn_cvt_pkrtz(v.z, v.w);
      const int cc = col4 >> 1, hf = col4 & 1;
      w1s[r][((cc ^ (r & 15)) << 1) | hf] = make_uint2(lo.u, hi.u);
    }
  }
  // ---- stage hs i-rows and j-rows (64x64 f32 -> f16), coalesced ----
  {
    const float4* hi4 = (const float4*)(hs + (size_t)(b * Nn + i0) * Fd);
    const float4* hj4 = (const float4*)(hs + (size_t)(b * Nn + j0) * Fd);
#pragma unroll
    for (int p = 0; p < 2; ++p) {
      const int k4 = p * 512 + t;            // 0..1023
      const int r = k4 >> 4, col4 = k4 & 15;
      const int cc = col4 >> 1, hf = col4 & 1;
      const int idx = ((cc ^ (r & 7)) << 1) | hf;
      {
        const float4 v = hi4[k4];
        H2 lo, hi_;
        lo.p  = __builtin_amdgcn_cvt_pkrtz(v.x, v.y);
        hi_.p = __builtin_amdgcn_cvt_pkrtz(v.z, v.w);
        hsI[r][idx] = make_uint2(lo.u, hi_.u);
      }
      {
        const float4 v = hj4[k4];
        H2 lo, hi_;
        lo.p  = __builtin_amdgcn_cvt_pkrtz(v.x, v.y);
        hi_.p = __builtin_amdgcn_cvt_pkrtz(v.z, v.w);
        hsJ[r][idx] = make_uint2(lo.u, hi_.u);
      }
    }
  }
  if (t < 32) {
    H2 wv2;
    wv2.v = (h2v){(_Float16)w2[2 * t], (_Float16)w2[2 * t + 1]};
    w2h[t] = wv2.u;
  }
  __syncthreads();

  // ---- phase 1: MFMA. waves 0-3 -> a-tile rows 16w..; waves 4-7 -> c-tile ----
  {
    const int l   = t & 63;
    const int w   = t >> 6;                  // 0..7
    const bool isA = (w < 4);
    const int wv  = w & 3;
    const int l15 = l & 15, l4 = l >> 4;
    const int mrow = wv * 16 + l15;          // A-frag row

    const uint2 (*hsX)[16] = isA ? hsI : hsJ;
    const int cbase = isA ? 0 : 8;           // w1 chunk base: a cols [0,64), c [64,128)

    f32x4 acc1[4] = {{0,0,0,0},{0,0,0,0},{0,0,0,0},{0,0,0,0}};

#pragma unroll
    for (int s = 0; s < 2; ++s) {
      U4F8 af;
      af.u = ((const uint4*)&hsX[mrow][0])[(s * 4 + l4) ^ (mrow & 7)];
#pragma unroll
      for (int nt = 0; nt < 4; ++nt) {
        const int rh = nt * 16 + l15;        // w1 row = output h
        U4F8 bf;
        bf.u = ((const uint4*)&w1s[rh][0])[(cbase + s * 4 + l4) ^ (rh & 15)];
        acc1[nt] = __builtin_amdgcn_mfma_f32_16x16x32_f16(af.v, bf.v, acc1[nt], 0, 0, 0);
      }
    }

    // epilogue: write tile (f16) into pair-layout LDS
    unsigned short* dTh = isA ? (unsigned short*)aT : (unsigned short*)cT;
#pragma unroll
    for (int nt = 0; nt < 4; ++nt) {
      const int n = nt * 16 + l15;           // h col 0..63
      const float bval = isA ? b1[n] : 0.f;
      const int chunk = n >> 3, pos = n & 7;
#pragma unroll
      for (int i = 0; i < 4; ++i) {
        const int row = wv * 16 + l4 * 4 + i;  // C/D: row=(lane>>4)*4+reg (verified r14)
        const int sw = chunk ^ ((row >> 2) & 7);
        HS1 x; x.h = (_Float16)(acc1[nt][i] + bval);
        dTh[row * 64 + sw * 8 + pos] = x.s;
      }
    }
  }
  __syncthreads();

  // ---- phase 2: pair (2x4 outputs/thread), bias folded into acc init ----
  const int jt  = t & 15;
  const int it2 = t >> 4;        // 0..31
  const int ib  = it2 * 2;
  const int jb  = jt * 4;
  const int sa  = (it2 >> 1) & 7;   // ((ib+u)>>2)&7, uniform for u=0,1
  const int sc  = jt & 7;

  const uint4* w2q = (const uint4*)w2h;
  const float bias2 = b2[0];

  float acc[2][4] = {{bias2, bias2, bias2, bias2},
                     {bias2, bias2, bias2, bias2}};

#pragma unroll 2
  for (int h8 = 0; h8 < 8; ++h8) {
    const uint4 wwu = w2q[h8];
    uint4 av[2], cv[4];
#pragma unroll
    for (int u = 0; u < 2; ++u) av[u] = aT[ib + u][h8 ^ sa];
#pragma unroll
    for (int v = 0; v < 4; ++v) cv[v] = cT[jb + v][h8 ^ sc];

#pragma unroll
    for (int u = 0; u < 2; ++u) {
      const unsigned au4[4] = {av[u].x, av[u].y, av[u].z, av[u].w};
#pragma unroll
      for (int v = 0; v < 4; ++v) {
        const unsigned cu4[4] = {cv[v].x, cv[v].y, cv[v].z, cv[v].w};
        const unsigned wu4[4] = {wwu.x, wwu.y, wwu.z, wwu.w};
#pragma unroll
        for (int m = 0; m < 4; ++m) {
          H2 za, zc, zw;
          za.u = au4[m]; zc.u = cu4[m]; zw.u = wu4[m];
          h2v z = __builtin_elementwise_max(za.v + zc.v, (h2v)(_Float16)0);
#if __has_builtin(__builtin_amdgcn_fdot2)
          acc[u][v] = __builtin_amdgcn_fdot2(z, zw.v, acc[u][v], false);
#else
          acc[u][v] = fmaf((float)z.x, (float)zw.v.x, acc[u][v]);
          acc[u][v] = fmaf((float)z.y, (float)zw.v.y, acc[u][v]);
#endif
        }
      }
    }
  }

  float* obase = out + (size_t)(b * Nn + i0 + ib) * Nn + j0;
  if (i0 == j0) {
    // on-diagonal block: per-element select
#pragma unroll
    for (int u = 0; u < 2; ++u) {
      const int i = ib + u;
      float4 o;
      o.x = (i == jb + 0) ? 1.0f : 1.f / (1.f + __expf(-acc[u][0]));
      o.y = (i == jb + 1) ? 1.0f : 1.f / (1.f + __expf(-acc[u][1]));
      o.z = (i == jb + 2) ? 1.0f : 1.f / (1.f + __expf(-acc[u][2]));
      o.w = (i == jb + 3) ? 1.0f : 1.f / (1.f + __expf(-acc[u][3]));
      ((float4*)(obase + (size_t)u * Nn))[jt] = o;
    }
  } else {
#pragma unroll
    for (int u = 0; u < 2; ++u) {
      float4 o;
      o.x = 1.f / (1.f + __expf(-acc[u][0]));
      o.y = 1.f / (1.f + __expf(-acc[u][1]));
      o.z = 1.f / (1.f + __expf(-acc[u][2]));
      o.w = 1.f / (1.f + __expf(-acc[u][3]));
      ((float4*)(obase + (size_t)u * Nn))[jt] = o;
    }
  }
}

extern "C" void kernel_launch(void* const* d_in, const int* in_sizes, int n_in,
                              void* d_out, int out_size, void* d_ws, size_t ws_size,
                              hipStream_t stream) {
  const float* hs = (const float*)d_in[0];
  const float* w1 = (const float*)d_in[1];
  const float* b1 = (const float*)d_in[2];
  const float* w2 = (const float*)d_in[3];
  const float* b2 = (const float*)d_in[4];
  float* out = (float*)d_out;

  dim3 grid(Nn / 64, Nn / 64, 16);   // (j-tiles, i-tiles, b) = 256 blocks
  fused_kernel<<<grid, 512, 0, stream>>>(hs, w1, b1, w2, b2, out);
}

// Round 20
// 12.058 us; speedup vs baseline: 1.0792x; 1.0792x over previous
//
#include <hip/hip_runtime.h>
#include <hip/hip_bf16.h>
#include <hip/hip_fp16.h>

// Problem: B=16, N=256, F=64, H=64
// out[b,i,j] = (i==j) ? 1 : sigmoid( sum_h relu(a[b,i,h]+c[b,j,h]) * w2[h] + b2 )
// a = hs @ w1[:, :64]^T + b1, c = hs @ w1[:, 64:]^T
//
// FINAL (r16, measured best 12.06us): single fused kernel, 512 thr/block,
// 256 blocks (64x64 tile/block). Staging f32->f16 LDS; phase-1 MFMA
// (waves 0-3 a-tile, 4-7 c-tile, verified 16x16x32 fragment mapping);
// phase-2 f16 packed pair loop (pk_add/pk_max/fdot2), 2x4 outputs/thread.
// Latency-bound floor: r8 (spill), r9 (swpipe), r17 (4 blk/CU), r18
// (stagger), r19 (micro-cuts) all neutral-or-worse.

#define Nn 256
#define Fd 64
#define Hd 64

typedef _Float16 h2v    __attribute__((ext_vector_type(2)));
typedef __fp16   fp16x2 __attribute__((ext_vector_type(2)));
typedef _Float16 f16x8  __attribute__((ext_vector_type(8)));
typedef float    f32x4  __attribute__((ext_vector_type(4)));
union H2   { h2v v; fp16x2 p; unsigned int u; };
union U4F8 { uint4 u; f16x8 v; };
union HS1  { _Float16 h; unsigned short s; };

__global__ __launch_bounds__(512) void fused_kernel(
    const float* __restrict__ hs, const float* __restrict__ w1,
    const float* __restrict__ b1, const float* __restrict__ w2,
    const float* __restrict__ b2, float* __restrict__ out) {
  __shared__ uint2 w1s[64][32];   // 16 KB: w1 f16, row h, chunk c at c^(h&15)
  __shared__ uint2 hsI[64][16];   //  8 KB: hs i-rows f16, chunk c at c^(r&7)
  __shared__ uint2 hsJ[64][16];   //  8 KB: hs j-rows f16
  __shared__ uint4 aT[64][8];     //  4 KB: a-tile f16 (pair layout)
  __shared__ uint4 cT[64][8];     //  4 KB: c-tile f16
  __shared__ unsigned int w2h[32];

  const int t  = threadIdx.x;
  const int b  = blockIdx.z;
  const int i0 = blockIdx.y * 64;
  const int j0 = blockIdx.x * 64;

  // ---- stage w1 (64x128 f32 -> f16 LDS), coalesced ----
  {
    const float4* w14 = (const float4*)w1;
#pragma unroll
    for (int p = 0; p < 4; ++p) {
      const int k4 = p * 512 + t;            // 0..2047
      const int r = k4 >> 5, col4 = k4 & 31;
      const float4 v = w14[k4];
      H2 lo, hi;
      lo.p = __builtin_amdgcn_cvt_pkrtz(v.x, v.y);
      hi.p = __builtin_amdgcn_cvt_pkrtz(v.z, v.w);
      const int cc = col4 >> 1, hf = col4 & 1;
      w1s[r][((cc ^ (r & 15)) << 1) | hf] = make_uint2(lo.u, hi.u);
    }
  }
  // ---- stage hs i-rows and j-rows (64x64 f32 -> f16), coalesced ----
  {
    const float4* hi4 = (const float4*)(hs + (size_t)(b * Nn + i0) * Fd);
    const float4* hj4 = (const float4*)(hs + (size_t)(b * Nn + j0) * Fd);
#pragma unroll
    for (int p = 0; p < 2; ++p) {
      const int k4 = p * 512 + t;            // 0..1023
      const int r = k4 >> 4, col4 = k4 & 15;
      const int cc = col4 >> 1, hf = col4 & 1;
      const int idx = ((cc ^ (r & 7)) << 1) | hf;
      {
        const float4 v = hi4[k4];
        H2 lo, hi_;
        lo.p  = __builtin_amdgcn_cvt_pkrtz(v.x, v.y);
        hi_.p = __builtin_amdgcn_cvt_pkrtz(v.z, v.w);
        hsI[r][idx] = make_uint2(lo.u, hi_.u);
      }
      {
        const float4 v = hj4[k4];
        H2 lo, hi_;
        lo.p  = __builtin_amdgcn_cvt_pkrtz(v.x, v.y);
        hi_.p = __builtin_amdgcn_cvt_pkrtz(v.z, v.w);
        hsJ[r][idx] = make_uint2(lo.u, hi_.u);
      }
    }
  }
  if (t < 32) {
    H2 wv2;
    wv2.v = (h2v){(_Float16)w2[2 * t], (_Float16)w2[2 * t + 1]};
    w2h[t] = wv2.u;
  }
  __syncthreads();

  // ---- phase 1: MFMA. waves 0-3 -> a-tile rows 16w..; waves 4-7 -> c-tile ----
  {
    const int l   = t & 63;
    const int w   = t >> 6;                  // 0..7
    const bool isA = (w < 4);
    const int wv  = w & 3;
    const int l15 = l & 15, l4 = l >> 4;
    const int mrow = wv * 16 + l15;          // A-frag row

    const uint2 (*hsX)[16] = isA ? hsI : hsJ;
    const int cbase = isA ? 0 : 8;           // w1 chunk base: a cols [0,64), c [64,128)

    f32x4 acc1[4] = {{0,0,0,0},{0,0,0,0},{0,0,0,0},{0,0,0,0}};

#pragma unroll
    for (int s = 0; s < 2; ++s) {
      U4F8 af;
      af.u = ((const uint4*)&hsX[mrow][0])[(s * 4 + l4) ^ (mrow & 7)];
#pragma unroll
      for (int nt = 0; nt < 4; ++nt) {
        const int rh = nt * 16 + l15;        // w1 row = output h
        U4F8 bf;
        bf.u = ((const uint4*)&w1s[rh][0])[(cbase + s * 4 + l4) ^ (rh & 15)];
        acc1[nt] = __builtin_amdgcn_mfma_f32_16x16x32_f16(af.v, bf.v, acc1[nt], 0, 0, 0);
      }
    }

    // epilogue: write tile (f16) into pair-layout LDS
    unsigned short* dTh = isA ? (unsigned short*)aT : (unsigned short*)cT;
#pragma unroll
    for (int nt = 0; nt < 4; ++nt) {
      const int n = nt * 16 + l15;           // h col 0..63
      const float bval = isA ? b1[n] : 0.f;
      const int chunk = n >> 3, pos = n & 7;
#pragma unroll
      for (int i = 0; i < 4; ++i) {
        const int row = wv * 16 + l4 * 4 + i;  // C/D: row=(lane>>4)*4+reg (verified r14)
        const int sw = chunk ^ ((row >> 2) & 7);
        HS1 x; x.h = (_Float16)(acc1[nt][i] + bval);
        dTh[row * 64 + sw * 8 + pos] = x.s;
      }
    }
  }
  __syncthreads();

  // ---- phase 2: pair (2x4 outputs/thread) ----
  const int jt  = t & 15;
  const int it2 = t >> 4;        // 0..31
  const int ib  = it2 * 2;
  const int jb  = jt * 4;
  const int sa  = (it2 >> 1) & 7;   // ((ib+u)>>2)&7, uniform for u=0,1
  const int sc  = jt & 7;

  const uint4* w2q = (const uint4*)w2h;

  float acc[2][4] = {{0.f}};

#pragma unroll 2
  for (int h8 = 0; h8 < 8; ++h8) {
    const uint4 wwu = w2q[h8];
    uint4 av[2], cv[4];
#pragma unroll
    for (int u = 0; u < 2; ++u) av[u] = aT[ib + u][h8 ^ sa];
#pragma unroll
    for (int v = 0; v < 4; ++v) cv[v] = cT[jb + v][h8 ^ sc];

#pragma unroll
    for (int u = 0; u < 2; ++u) {
      const unsigned au4[4] = {av[u].x, av[u].y, av[u].z, av[u].w};
#pragma unroll
      for (int v = 0; v < 4; ++v) {
        const unsigned cu4[4] = {cv[v].x, cv[v].y, cv[v].z, cv[v].w};
        const unsigned wu4[4] = {wwu.x, wwu.y, wwu.z, wwu.w};
#pragma unroll
        for (int m = 0; m < 4; ++m) {
          H2 za, zc, zw;
          za.u = au4[m]; zc.u = cu4[m]; zw.u = wu4[m];
          h2v z = __builtin_elementwise_max(za.v + zc.v, (h2v)(_Float16)0);
#if __has_builtin(__builtin_amdgcn_fdot2)
          acc[u][v] = __builtin_amdgcn_fdot2(z, zw.v, acc[u][v], false);
#else
          acc[u][v] = fmaf((float)z.x, (float)zw.v.x, acc[u][v]);
          acc[u][v] = fmaf((float)z.y, (float)zw.v.y, acc[u][v]);
#endif
        }
      }
    }
  }

  const float bias2 = b2[0];
#pragma unroll
  for (int u = 0; u < 2; ++u) {
    const int i = i0 + ib + u;
    float4 o;
    o.x = (i == j0 + jb + 0) ? 1.0f : 1.f / (1.f + __expf(-(acc[u][0] + bias2)));
    o.y = (i == j0 + jb + 1) ? 1.0f : 1.f / (1.f + __expf(-(acc[u][1] + bias2)));
    o.z = (i == j0 + jb + 2) ? 1.0f : 1.f / (1.f + __expf(-(acc[u][2] + bias2)));
    o.w = (i == j0 + jb + 3) ? 1.0f : 1.f / (1.f + __expf(-(acc[u][3] + bias2)));
    ((float4*)(out + (size_t)(b * Nn + i) * Nn + j0))[jt] = o;
  }
}

extern "C" void kernel_launch(void* const* d_in, const int* in_sizes, int n_in,
                              void* d_out, int out_size, void* d_ws, size_t ws_size,
                              hipStream_t stream) {
  const float* hs = (const float*)d_in[0];
  const float* w1 = (const float*)d_in[1];
  const float* b1 = (const float*)d_in[2];
  const float* w2 = (const float*)d_in[3];
  const float* b2 = (const float*)d_in[4];
  float* out = (float*)d_out;

  dim3 grid(Nn / 64, Nn / 64, 16);   // (j-tiles, i-tiles, b) = 256 blocks
  fused_kernel<<<grid, 512, 0, stream>>>(hs, w1, b1, w2, b2, out);
}